// Round 17
// baseline (303.273 us; speedup 1.0000x reference)
//
#include <hip/hip_runtime.h>
#include <cstdint>
#include <cstddef>

#define DMODEL 1024
#define DH 2048
#define BATCH 2
#define SEQ 4096
#define MROWS (BATCH*SEQ)    // 8192
#define CHUNK 64
#define NCHUNK (SEQ/CHUNK)   // 64

typedef unsigned short u16;
typedef unsigned int u32;
typedef __attribute__((ext_vector_type(8))) short bf16x8;
typedef __attribute__((ext_vector_type(4))) float f32x4;

__device__ __forceinline__ u16 f2bf(float f) {
    union { float f; unsigned u; } v; v.f = f;
    unsigned r = v.u + 0x7FFFu + ((v.u >> 16) & 1u);
    return (u16)(r >> 16);
}
__device__ __forceinline__ float bf2f(u16 h) {
    union { unsigned u; float f; } v; v.u = ((unsigned)h) << 16; return v.f;
}

__device__ __forceinline__ float softplus_fast(float x) {
    if (x < -4.f) return __expf(x);
    return (x > 0.f) ? (x + log1pf(__expf(-x))) : log1pf(__expf(x));
}
__device__ __forceinline__ float silu_fast(float v) {
    return v * __fdividef(1.f, 1.f + __expf(-v));
}

// ---------------- f32 -> bf16, 4 elems/thread (single buffer) ----------------
__global__ void cvt_bf16(const float* __restrict__ src, u16* __restrict__ dst, int n4) {
    int i = blockIdx.x * blockDim.x + threadIdx.x;
    if (i >= n4) return;
    const float4 v = reinterpret_cast<const float4*>(src)[i];
    ushort4 o;
    o.x = f2bf(v.x); o.y = f2bf(v.y); o.z = f2bf(v.z); o.w = f2bf(v.w);
    reinterpret_cast<ushort4*>(dst)[i] = o;
}

// ---------------- fused multi-buffer f32 -> bf16 (all weights, one launch) ----------------
struct CvtArgs {
    const float* src[7];
    u16* dst[7];
    unsigned cum[8];   // cumulative float4 counts; cum[7] = total
};
__global__ void cvt_multi(CvtArgs a) {
    const unsigned i = blockIdx.x * blockDim.x + threadIdx.x;
    if (i >= a.cum[7]) return;
    int s = 0;
    while (i >= a.cum[s+1]) ++s;
    const unsigned off = i - a.cum[s];
    const float4 v = reinterpret_cast<const float4*>(a.src[s])[off];
    ushort4 o;
    o.x = f2bf(v.x); o.y = f2bf(v.y); o.z = f2bf(v.z); o.w = f2bf(v.w);
    reinterpret_cast<ushort4*>(a.dst[s])[off] = o;
}

// ---------------- GEMM: C[M,N] = A[M,K] @ B[N,K]^T  (bf16 in, f32 acc) ----------------
// R17 = R16 verified structure. 128x128 tile, BK=64, 256 thr, single-buffered 32 KB
// tile LDS (+8 KB epilogue headroom = 40 KB -> exactly 4 blocks/CU; regs 60+64 AGPR
// -> exactly 4 waves/SIMD), gload_lds width-16, XOR swizzle both sides, 8x8 supertile
// XCD raster, coalesced 2-round LDS epilogue.
// NEW: TWOK runs as two clean segment loops (no per-iteration operand select).
// EP 0: Cb = bf16(acc + b1 [+ b2])
// EP 2: Cb = bf16(aux * silu(acc))             (gate; aux bf16)
// EP 3: C  = aux + acc                         (final residual, f32 out; aux bf16)
// EP 4: N=2*DH split: n0<DH -> Cb=bf16(softplus(acc+b1)) else Cb2=bf16(acc+b2)
__device__ __forceinline__ void gload_lds16(const void* g, void* l) {
    __builtin_amdgcn_global_load_lds(
        (const __attribute__((address_space(1))) void*)g,
        (__attribute__((address_space(3))) void*)l,
        16, 0, 0);
}

template<int EP, bool TWOK>
__global__ __launch_bounds__(256, 4) void gemm_bt(
    const u16* __restrict__ A1, const u16* __restrict__ B1, int K1,
    const u16* __restrict__ A2, const u16* __restrict__ B2, int K2,
    float* __restrict__ C, u16* __restrict__ Cb, u16* __restrict__ Cb2,
    const float* __restrict__ bias, const float* __restrict__ bias2,
    const u16* __restrict__ aux,
    int M, int N)
{
    __shared__ __align__(16) char smem[40960];
    u16* As = (u16*)smem;              // [128 rows][8 chunks of 16B], swizzled
    u16* Bs = (u16*)(smem + 16384);
    float* ep = (float*)smem;          // epilogue scratch [64][132] f32 (33.8 KB)

    const int tid = threadIdx.x;

    // 8x8 supertile rasterization in XCD-contiguous chunks (bijective for our grids)
    const int nwg = gridDim.x * gridDim.y;
    int wg = blockIdx.y * gridDim.x + blockIdx.x;
    wg = (wg & 7) * (nwg >> 3) + (wg >> 3);
    const int stile = wg >> 6;
    const int t64   = wg & 63;
    const int nSn   = gridDim.x >> 3;
    const int sm = (nSn > 0) ? stile / nSn : stile;
    const int sn = (nSn > 0) ? stile - sm * nSn : 0;
    const int m0 = (sm * 8 + (t64 >> 3)) * 128;
    const int n0 = (sn * 8 + (t64 & 7)) * 128;

    const int wave = tid >> 6, lane = tid & 63;
    const int wr = (wave >> 1) * 64;   // 2x2 wave grid, 64x64 per wave
    const int wc = (wave & 1) * 64;
    const int fr = lane & 15, fq = lane >> 4;

    f32x4 acc[4][4];
    #pragma unroll
    for (int m = 0; m < 4; m++)
        #pragma unroll
        for (int n = 0; n < 4; n++) acc[m][n] = f32x4{0.f, 0.f, 0.f, 0.f};

    auto run_seg = [&](const u16* __restrict__ A, const u16* __restrict__ B, int K) {
        const int nt = K >> 6;
        for (int t = 0; t < nt; ++t) {
            const int k0 = t << 6;
            #pragma unroll
            for (int i = 0; i < 4; ++i) {
                const int g = i*256 + tid;
                const int r = g >> 3;
                const int ch = (g & 7) ^ (r & 7);   // pre-swizzled source chunk
                gload_lds16(A + (size_t)(m0 + r)*K + (k0 + ch*8), (char*)As + (size_t)g*16);
                gload_lds16(B + (size_t)(n0 + r)*K + (k0 + ch*8), (char*)Bs + (size_t)g*16);
            }
            __syncthreads();

            #pragma unroll
            for (int kk = 0; kk < 2; ++kk) {
                bf16x8 af[4], bfr[4];
                #pragma unroll
                for (int m = 0; m < 4; m++) {
                    const int r = wr + m*16 + fr;
                    af[m] = *reinterpret_cast<const bf16x8*>(
                        (const char*)As + r*128 + (((kk*4 + fq) ^ (r & 7)) * 16));
                }
                #pragma unroll
                for (int n = 0; n < 4; n++) {
                    const int r = wc + n*16 + fr;
                    bfr[n] = *reinterpret_cast<const bf16x8*>(
                        (const char*)Bs + r*128 + (((kk*4 + fq) ^ (r & 7)) * 16));
                }
                #pragma unroll
                for (int m = 0; m < 4; m++)
                    #pragma unroll
                    for (int n = 0; n < 4; n++)
                        acc[m][n] = __builtin_amdgcn_mfma_f32_16x16x32_bf16(af[m], bfr[n], acc[m][n], 0, 0, 0);
            }
            __syncthreads();
        }
    };
    run_seg(A1, B1, K1);
    if constexpr (TWOK) run_seg(A2, B2, K2);

    // ---------- coalesced epilogue: 2 rounds of 64 rows through LDS ----------
    const bool isDelta = (EP == 4) ? (n0 < DH) : false;
    #pragma unroll
    for (int c = 0; c < 2; ++c) {
        if ((wave >> 1) == c) {          // the 2 waves owning rows [c*64, c*64+64)
            #pragma unroll
            for (int m = 0; m < 4; m++)
                #pragma unroll
                for (int n = 0; n < 4; n++) {
                    const int col = wc + n*16 + fr;
                    #pragma unroll
                    for (int j = 0; j < 4; j++)
                        ep[(m*16 + fq*4 + j)*132 + col] = acc[m][n][j];
                }
        }
        __syncthreads();
        #pragma unroll
        for (int p = 0; p < 8; ++p) {
            const int idx = p*256 + tid;        // 2048 float4 per round
            const int row = idx >> 5, c4 = idx & 31;
            float4 v = *reinterpret_cast<const float4*>(&ep[row*132 + c4*4]);
            const int rg   = m0 + c*64 + row;
            const int colg = n0 + c4*4;
            if constexpr (EP == 4) {
                const int cc = isDelta ? colg : (colg - DH);
                const float4 bv = *reinterpret_cast<const float4*>(
                    (isDelta ? bias : bias2) + cc);
                ushort4 o;
                if (isDelta) {
                    o.x = f2bf(softplus_fast(v.x + bv.x));
                    o.y = f2bf(softplus_fast(v.y + bv.y));
                    o.z = f2bf(softplus_fast(v.z + bv.z));
                    o.w = f2bf(softplus_fast(v.w + bv.w));
                } else {
                    o.x = f2bf(v.x + bv.x); o.y = f2bf(v.y + bv.y);
                    o.z = f2bf(v.z + bv.z); o.w = f2bf(v.w + bv.w);
                }
                *reinterpret_cast<ushort4*>((isDelta ? Cb : Cb2) + (size_t)rg*DH + cc) = o;
            } else {
                if (bias) {
                    const float4 b1 = *reinterpret_cast<const float4*>(bias + colg);
                    v.x += b1.x; v.y += b1.y; v.z += b1.z; v.w += b1.w;
                }
                if (bias2) {
                    const float4 b2 = *reinterpret_cast<const float4*>(bias2 + colg);
                    v.x += b2.x; v.y += b2.y; v.z += b2.z; v.w += b2.w;
                }
                const size_t gidx = (size_t)rg * N + colg;
                if constexpr (EP == 0) {
                    ushort4 o = { f2bf(v.x), f2bf(v.y), f2bf(v.z), f2bf(v.w) };
                    *reinterpret_cast<ushort4*>(Cb + gidx) = o;
                } else if constexpr (EP == 2) {
                    const ushort4 ab = *reinterpret_cast<const ushort4*>(aux + gidx);
                    ushort4 o = { f2bf(bf2f(ab.x) * silu_fast(v.x)),
                                  f2bf(bf2f(ab.y) * silu_fast(v.y)),
                                  f2bf(bf2f(ab.z) * silu_fast(v.z)),
                                  f2bf(bf2f(ab.w) * silu_fast(v.w)) };
                    *reinterpret_cast<ushort4*>(Cb + gidx) = o;
                } else {   // EP 3
                    const ushort4 ab = *reinterpret_cast<const ushort4*>(aux + gidx);
                    float4 o = { bf2f(ab.x) + v.x, bf2f(ab.y) + v.y,
                                 bf2f(ab.z) + v.z, bf2f(ab.w) + v.w };
                    *reinterpret_cast<float4*>(C + gidx) = o;
                }
            }
        }
        __syncthreads();
    }
}

// ---------------- depthwise conv3 (pad 1, per seq of 4096) + silu, bf16x8 ----------------
__global__ void conv_silu8(const u16* __restrict__ x1, const float* __restrict__ cw,
                           const float* __restrict__ cb, u16* __restrict__ xab) {
    int t = blockIdx.x * blockDim.x + threadIdx.x;
    int c8  = t & (DMODEL/8 - 1);
    int row = t >> 7;
    int l = row & (SEQ - 1);
    const int c0 = c8 * 8;
    const size_t i0 = (size_t)row * DMODEL + c0;
    bf16x8 v0 = *reinterpret_cast<const bf16x8*>(x1 + i0);
    bf16x8 vm = {}; if (l > 0)       vm = *reinterpret_cast<const bf16x8*>(x1 + i0 - DMODEL);
    bf16x8 vp = {}; if (l < SEQ - 1) vp = *reinterpret_cast<const bf16x8*>(x1 + i0 + DMODEL);
    if (l == 0)       vm = bf16x8{};
    if (l == SEQ - 1) vp = bf16x8{};
    bf16x8 o;
    #pragma unroll
    for (int j = 0; j < 8; ++j) {
        const int c = c0 + j;
        float v = cw[c*3+0]*bf2f((u16)vm[j]) + cw[c*3+1]*bf2f((u16)v0[j])
                + cw[c*3+2]*bf2f((u16)vp[j]) + cb[c];
        o[j] = (short)f2bf(silu_fast(v));
    }
    *reinterpret_cast<bf16x8*>(xab + i0) = o;
}

// ---------------- SSM chunked scan: 4 channels/thread, dwordx2 loads, prefetched ----------------
__global__ void scan_chunks(const u16* __restrict__ delta, const u16* __restrict__ pBv,
                            const float* __restrict__ Avec,
                            float* __restrict__ cA, float* __restrict__ cB) {
    const int c = (blockIdx.x * blockDim.x + threadIdx.x) * 4;
    const int q = blockIdx.y;
    const int b = blockIdx.z;
    const float4 Av = *reinterpret_cast<const float4*>(Avec + c);
    const float Aa[4] = { Av.x, Av.y, Av.z, Av.w };
    float hA[4] = {1.f,1.f,1.f,1.f}, hB[4] = {0.f,0.f,0.f,0.f};
    size_t base = ((size_t)b*SEQ + q*CHUNK)*DH + c;
    uint2 du = *reinterpret_cast<const uint2*>(delta + base);
    uint2 pu = *reinterpret_cast<const uint2*>(pBv + base);
    for (int j = 0; j < CHUNK; ++j) {
        uint2 dn = {0,0}, pn = {0,0};
        if (j + 1 < CHUNK) {                       // prefetch next step
            dn = *reinterpret_cast<const uint2*>(delta + base + DH);
            pn = *reinterpret_cast<const uint2*>(pBv + base + DH);
        }
        const float d[4] = { bf2f((u16)(du.x & 0xFFFF)), bf2f((u16)(du.x >> 16)),
                             bf2f((u16)(du.y & 0xFFFF)), bf2f((u16)(du.y >> 16)) };
        const float pv[4] = { bf2f((u16)(pu.x & 0xFFFF)), bf2f((u16)(pu.x >> 16)),
                              bf2f((u16)(pu.y & 0xFFFF)), bf2f((u16)(pu.y >> 16)) };
        #pragma unroll
        for (int k = 0; k < 4; ++k) {
            const float a = __expf(d[k] * Aa[k]);
            hA[k] *= a;
            hB[k] = a*hB[k] + d[k]*pv[k];
        }
        du = dn; pu = pn; base += DH;
    }
    size_t o = ((size_t)b*NCHUNK + q)*DH + c;
    *reinterpret_cast<float4*>(cA + o) = float4{ hA[0], hA[1], hA[2], hA[3] };
    *reinterpret_cast<float4*>(cB + o) = float4{ hB[0], hB[1], hB[2], hB[3] };
}

__global__ void scan_prefix(const float* __restrict__ cA, const float* __restrict__ cB,
                            float* __restrict__ cH) {
    const int t = blockIdx.x * blockDim.x + threadIdx.x;
    const int b = t >> 11;
    const int c = t & (DH - 1);
    float h = 0.f;
    size_t o = ((size_t)b*NCHUNK)*DH + c;
    float a = cA[o], bb = cB[o];
    for (int q = 0; q < NCHUNK; ++q) {
        const size_t on = o + DH;
        float a2 = 0.f, b2 = 0.f;
        if (q + 1 < NCHUNK) { a2 = cA[on]; b2 = cB[on]; }
        cH[o] = h;
        h = a*h + bb;
        a = a2; bb = b2; o = on;
    }
}

__global__ void scan_apply(const u16* __restrict__ delta, const u16* __restrict__ pBv,
                           const float* __restrict__ Avec, const float* __restrict__ cH,
                           u16* __restrict__ hstb) {
    const int c = (blockIdx.x * blockDim.x + threadIdx.x) * 4;
    const int q = blockIdx.y;
    const int b = blockIdx.z;
    const float4 Av = *reinterpret_cast<const float4*>(Avec + c);
    const float Aa[4] = { Av.x, Av.y, Av.z, Av.w };
    const float4 hv = *reinterpret_cast<const float4*>(cH + ((size_t)b*NCHUNK + q)*DH + c);
    float h[4] = { hv.x, hv.y, hv.z, hv.w };
    size_t base = ((size_t)b*SEQ + q*CHUNK)*DH + c;
    uint2 du = *reinterpret_cast<const uint2*>(delta + base);
    uint2 pu = *reinterpret_cast<const uint2*>(pBv + base);
    for (int j = 0; j < CHUNK; ++j) {
        uint2 dn = {0,0}, pn = {0,0};
        if (j + 1 < CHUNK) {
            dn = *reinterpret_cast<const uint2*>(delta + base + DH);
            pn = *reinterpret_cast<const uint2*>(pBv + base + DH);
        }
        const float d[4] = { bf2f((u16)(du.x & 0xFFFF)), bf2f((u16)(du.x >> 16)),
                             bf2f((u16)(du.y & 0xFFFF)), bf2f((u16)(du.y >> 16)) };
        const float pv[4] = { bf2f((u16)(pu.x & 0xFFFF)), bf2f((u16)(pu.x >> 16)),
                              bf2f((u16)(pu.y & 0xFFFF)), bf2f((u16)(pu.y >> 16)) };
        ushort4 o;
        #pragma unroll
        for (int k = 0; k < 4; ++k) {
            const float a = __expf(d[k] * Aa[k]);
            h[k] = a*h[k] + d[k]*pv[k];
        }
        o.x = f2bf(h[0]); o.y = f2bf(h[1]); o.z = f2bf(h[2]); o.w = f2bf(h[3]);
        *reinterpret_cast<ushort4*>(hstb + base) = o;
        du = dn; pu = pn; base += DH;
    }
}

// ---------------- host ----------------
extern "C" void kernel_launch(void* const* d_in, const int* in_sizes, int n_in,
                              void* d_out, int out_size, void* d_ws, size_t ws_size,
                              hipStream_t stream) {
    const float* x      = (const float*)d_in[0];
    const float* W1     = (const float*)d_in[1];
    const float* conv_w = (const float*)d_in[2];
    const float* conv_b = (const float*)d_in[3];
    const float* Avec   = (const float*)d_in[4];
    const float* Wb     = (const float*)d_in[5];
    const float* bb     = (const float*)d_in[6];
    const float* Wc     = (const float*)d_in[7];
    const float* bc     = (const float*)d_in[8];
    const float* Wd     = (const float*)d_in[9];
    const float* bd     = (const float*)d_in[10];
    const float* Wdelta = (const float*)d_in[11];
    const float* bdelta = (const float*)d_in[12];
    const float* W2     = (const float*)d_in[13];
    const float* Wlast  = (const float*)d_in[14];
    float* out = (float*)d_out;
    (void)in_sizes; (void)n_in; (void)out_size;

    struct Ptrs {
        u16 *w1, *wdel, *wb, *wd, *wc, *w2, *wl;
        float *cA, *cB, *cH;
        u16 *xb, *x1b, *xab, *delta, *pBv, *ossb, *hstb, *zb;
        size_t total;
    };
    auto layout = [&](int passes) -> Ptrs {
        Ptrs P{};
        const size_t Mp = MROWS / passes;
        const int nb = BATCH / passes;
        size_t off = 0;
        auto al = [&](size_t bytes) -> char* {
            char* p = (char*)d_ws + off; off += (bytes + 255) & ~(size_t)255; return p;
        };
        P.w1   = (u16*)al((size_t)DMODEL*DMODEL*2);
        P.wdel = (u16*)al((size_t)DH*DMODEL*2);
        P.wb   = (u16*)al((size_t)DH*DMODEL*2);
        P.wd   = (u16*)al((size_t)DMODEL*DMODEL*2);
        P.wc   = (u16*)al((size_t)DMODEL*DH*2);
        P.w2   = (u16*)al((size_t)DMODEL*DMODEL*2);
        P.wl   = (u16*)al((size_t)DMODEL*DMODEL*2);
        P.cA  = (float*)al((size_t)nb*NCHUNK*DH*4);
        P.cB  = (float*)al((size_t)nb*NCHUNK*DH*4);
        P.cH  = (float*)al((size_t)nb*NCHUNK*DH*4);
        char* RA = al(Mp*DMODEL*2);                   // xb -> ossb
        char* RB = al(Mp*DMODEL*2);                   // x1b -> zb
        char* RC = al(Mp*DMODEL*2);                   // xab
        char* RD = al(Mp*DH*2);                       // delta
        char* RE = al(Mp*DH*2);                       // pBv
        char* RF = al(Mp*DH*2);                       // hstb
        P.xb    = (u16*)RA; P.ossb = (u16*)RA;
        P.x1b   = (u16*)RB; P.zb   = (u16*)RB;
        P.xab   = (u16*)RC;
        P.delta = (u16*)RD;
        P.pBv   = (u16*)RE;
        P.hstb  = (u16*)RF;
        P.total = off;
        return P;
    };

    int passes = (ws_size >= layout(1).total) ? 1 : 2;
    Ptrs P = layout(passes);
    if (ws_size < P.total) return;
    const int Mp = MROWS / passes;
    const int nb = BATCH / passes;

    const dim3 blk(256);

    // one fused launch: convert all 7 weights into dedicated slots
    {
        CvtArgs a{};
        const float* srcs[7] = { W1, Wdelta, Wb, Wd, Wc, W2, Wlast };
        u16* dsts[7] = { P.w1, P.wdel, P.wb, P.wd, P.wc, P.w2, P.wl };
        const unsigned n4s[7] = {
            DMODEL*DMODEL/4, DH*DMODEL/4, DH*DMODEL/4, DMODEL*DMODEL/4,
            DMODEL*DH/4, DMODEL*DMODEL/4, DMODEL*DMODEL/4 };
        unsigned cum = 0;
        for (int s = 0; s < 7; ++s) { a.src[s] = srcs[s]; a.dst[s] = dsts[s]; a.cum[s] = cum; cum += n4s[s]; }
        a.cum[7] = cum;
        cvt_multi<<<dim3((cum + 255)/256), blk, 0, stream>>>(a);
    }

    const dim3 gD (DMODEL/128, Mp/128);   // 8 x 64 = 512 blocks (1-pass)
    const dim3 gDB(2*DH/128,   Mp/128);   // 32 x 64 = 2048 blocks (merged delta|pBv)

    for (int p = 0; p < passes; ++p) {
        const float* x_p  = x  + (size_t)p*Mp*DMODEL;
        float*      out_p = out + (size_t)p*Mp*DMODEL;

        {   // x -> bf16
            int n4 = (int)((size_t)Mp*DMODEL / 4);
            cvt_bf16<<<dim3((n4 + 255)/256), blk, 0, stream>>>(x_p, P.xb, n4);
        }
        // x1 = x @ W1^T
        gemm_bt<0,false><<<gD, blk, 0, stream>>>(P.xb, P.w1, DMODEL, nullptr, nullptr, 0,
                                                 nullptr, P.x1b, nullptr, nullptr, nullptr, nullptr, Mp, DMODEL);
        // xa = silu(conv3(x1))
        conv_silu8<<<dim3(Mp*DMODEL/8/256), blk, 0, stream>>>(P.x1b, conv_w, conv_b, P.xab);
        // merged: delta = softplus(xa@Wdelta^T + bdelta), pBv = xa@Wb^T + bb
        gemm_bt<4,false><<<gDB, blk, 0, stream>>>(P.xab, P.wdel, DMODEL, nullptr, nullptr, 0,
                                                  nullptr, P.delta, P.pBv, bdelta, bb, nullptr, Mp, 2*DH);
        // chunked scan -> h_st (bf16)
        scan_chunks<<<dim3(DH/4/256, NCHUNK, nb), blk, 0, stream>>>(P.delta, P.pBv, Avec, P.cA, P.cB);
        scan_prefix<<<dim3(nb*DH/256), blk, 0, stream>>>(P.cA, P.cB, P.cH);
        scan_apply <<<dim3(DH/4/256, NCHUNK, nb), blk, 0, stream>>>(P.delta, P.pBv, Avec, P.cH, P.hstb);
        // ossb = bf16(xa @ Wd^T + h_st @ Wc^T + bd + bc)
        gemm_bt<0,true><<<gD, blk, 0, stream>>>(P.xab, P.wd, DMODEL, P.hstb, P.wc, DH,
                                                nullptr, P.ossb, nullptr, bd, bc, nullptr, Mp, DMODEL);
        // z = ossb * silu(ossb @ W2^T)
        gemm_bt<2,false><<<gD, blk, 0, stream>>>(P.ossb, P.w2, DMODEL, nullptr, nullptr, 0,
                                                 nullptr, P.zb, nullptr, nullptr, nullptr, P.ossb, Mp, DMODEL);
        // out = ossb + z @ Wlast^T
        gemm_bt<3,false><<<gD, blk, 0, stream>>>(P.zb, P.wl, DMODEL, nullptr, nullptr, 0,
                                                 out_p, nullptr, nullptr, nullptr, nullptr, P.ossb, Mp, DMODEL);
    }
}

// Round 18
// 297.817 us; speedup vs baseline: 1.0183x; 1.0183x over previous
//
#include <hip/hip_runtime.h>
#include <cstdint>
#include <cstddef>

#define DMODEL 1024
#define DH 2048
#define BATCH 2
#define SEQ 4096
#define MROWS (BATCH*SEQ)    // 8192
#define CHUNK 64
#define NCHUNK (SEQ/CHUNK)   // 64

typedef unsigned short u16;
typedef unsigned int u32;
typedef __attribute__((ext_vector_type(8))) short bf16x8;
typedef __attribute__((ext_vector_type(4))) float f32x4;

__device__ __forceinline__ u16 f2bf(float f) {
    union { float f; unsigned u; } v; v.f = f;
    unsigned r = v.u + 0x7FFFu + ((v.u >> 16) & 1u);
    return (u16)(r >> 16);
}
__device__ __forceinline__ float bf2f(u16 h) {
    union { unsigned u; float f; } v; v.u = ((unsigned)h) << 16; return v.f;
}

__device__ __forceinline__ float softplus_fast(float x) {
    if (x < -4.f) return __expf(x);
    return (x > 0.f) ? (x + log1pf(__expf(-x))) : log1pf(__expf(x));
}
__device__ __forceinline__ float silu_fast(float v) {
    return v * __fdividef(1.f, 1.f + __expf(-v));
}

// ---------------- f32 -> bf16, 4 elems/thread (single buffer) ----------------
__global__ void cvt_bf16(const float* __restrict__ src, u16* __restrict__ dst, int n4) {
    int i = blockIdx.x * blockDim.x + threadIdx.x;
    if (i >= n4) return;
    const float4 v = reinterpret_cast<const float4*>(src)[i];
    ushort4 o;
    o.x = f2bf(v.x); o.y = f2bf(v.y); o.z = f2bf(v.z); o.w = f2bf(v.w);
    reinterpret_cast<ushort4*>(dst)[i] = o;
}

// ---------------- fused multi-buffer f32 -> bf16 (all weights, one launch) ----------------
struct CvtArgs {
    const float* src[7];
    u16* dst[7];
    unsigned cum[8];   // cumulative float4 counts; cum[7] = total
};
__global__ void cvt_multi(CvtArgs a) {
    const unsigned i = blockIdx.x * blockDim.x + threadIdx.x;
    if (i >= a.cum[7]) return;
    int s = 0;
    while (i >= a.cum[s+1]) ++s;
    const unsigned off = i - a.cum[s];
    const float4 v = reinterpret_cast<const float4*>(a.src[s])[off];
    ushort4 o;
    o.x = f2bf(v.x); o.y = f2bf(v.y); o.z = f2bf(v.z); o.w = f2bf(v.w);
    reinterpret_cast<ushort4*>(a.dst[s])[off] = o;
}

// ---------------- GEMM: C[M,N] = A[M,K] @ B[N,K]^T  (bf16 in, f32 acc) ----------------
// R18 = R16 verified structure, BN-templated.
//   BN=128 (merged EP4, N=4096, 2048 blocks): unchanged R16 config.
//   BN=64  (N=1024 GEMMs): grid 1024 blocks -> exactly 4 blocks/CU resident (these
//   ran 512 blocks = 2/CU before; R12->R13 proved 2->4 blocks/CU = -26% on this family).
// 128xBN tile, BK=64, 256 thr (2x2 waves of 64x(BN/2)), single-buffered LDS,
// gload_lds width-16, XOR swizzle both sides, 8x8 supertile XCD raster,
// coalesced 2-round LDS epilogue.
// EP 0: Cb = bf16(acc + b1 [+ b2])
// EP 2: Cb = bf16(aux * silu(acc))             (gate; aux bf16)
// EP 3: C  = aux + acc                         (final residual, f32 out; aux bf16)
// EP 4: N=2*DH split: n0<DH -> Cb=bf16(softplus(acc+b1)) else Cb2=bf16(acc+b2)
__device__ __forceinline__ void gload_lds16(const void* g, void* l) {
    __builtin_amdgcn_global_load_lds(
        (const __attribute__((address_space(1))) void*)g,
        (__attribute__((address_space(3))) void*)l,
        16, 0, 0);
}

template<int EP, bool TWOK, int BN>
__global__ __launch_bounds__(256, 4) void gemm_bt(
    const u16* __restrict__ A1, const u16* __restrict__ B1, int K1,
    const u16* __restrict__ A2, const u16* __restrict__ B2, int K2,
    float* __restrict__ C, u16* __restrict__ Cb, u16* __restrict__ Cb2,
    const float* __restrict__ bias, const float* __restrict__ bias2,
    const u16* __restrict__ aux,
    int M, int N)
{
    constexpr int FN   = BN / 32;            // B fragments per wave
    constexpr int EPS  = BN + 4;             // epilogue row stride (floats)
    constexpr int SMEM = (BN == 128) ? 40960 : 24576;
    __shared__ __align__(16) char smem[SMEM];
    u16* As = (u16*)smem;                    // [128 rows][8 chunks of 16B], swizzled
    u16* Bs = (u16*)(smem + 16384);          // [BN rows][8 chunks of 16B]
    float* ep = (float*)smem;                // epilogue scratch [64][BN+4] f32

    const int tid = threadIdx.x;

    // 8x8 supertile rasterization in XCD-contiguous chunks (bijective for our grids)
    const int nwg = gridDim.x * gridDim.y;
    int wg = blockIdx.y * gridDim.x + blockIdx.x;
    wg = (wg & 7) * (nwg >> 3) + (wg >> 3);
    const int stile = wg >> 6;
    const int t64   = wg & 63;
    const int nSn   = gridDim.x >> 3;
    const int sm = (nSn > 0) ? stile / nSn : stile;
    const int sn = (nSn > 0) ? stile - sm * nSn : 0;
    const int m0 = (sm * 8 + (t64 >> 3)) * 128;
    const int n0 = (sn * 8 + (t64 & 7)) * BN;

    const int wave = tid >> 6, lane = tid & 63;
    const int wr = (wave >> 1) * 64;         // 2 m-groups of 64
    const int wc = (wave & 1) * (BN / 2);    // 2 n-groups of BN/2
    const int fr = lane & 15, fq = lane >> 4;

    f32x4 acc[4][FN];
    #pragma unroll
    for (int m = 0; m < 4; m++)
        #pragma unroll
        for (int n = 0; n < FN; n++) acc[m][n] = f32x4{0.f, 0.f, 0.f, 0.f};

    auto run_seg = [&](const u16* __restrict__ A, const u16* __restrict__ B, int K) {
        const int nt = K >> 6;
        for (int t = 0; t < nt; ++t) {
            const int k0 = t << 6;
            #pragma unroll
            for (int i = 0; i < 4; ++i) {            // A: 1024 granules
                const int g = i*256 + tid;
                const int r = g >> 3;
                const int ch = (g & 7) ^ (r & 7);    // pre-swizzled source chunk
                gload_lds16(A + (size_t)(m0 + r)*K + (k0 + ch*8), (char*)As + (size_t)g*16);
            }
            #pragma unroll
            for (int i = 0; i < BN/32; ++i) {        // B: BN*8 granules
                const int g = i*256 + tid;
                const int r = g >> 3;
                const int ch = (g & 7) ^ (r & 7);
                gload_lds16(B + (size_t)(n0 + r)*K + (k0 + ch*8), (char*)Bs + (size_t)g*16);
            }
            __syncthreads();

            #pragma unroll
            for (int kk = 0; kk < 2; ++kk) {
                bf16x8 af[4], bfr[FN];
                #pragma unroll
                for (int m = 0; m < 4; m++) {
                    const int r = wr + m*16 + fr;
                    af[m] = *reinterpret_cast<const bf16x8*>(
                        (const char*)As + r*128 + (((kk*4 + fq) ^ (r & 7)) * 16));
                }
                #pragma unroll
                for (int n = 0; n < FN; n++) {
                    const int r = wc + n*16 + fr;
                    bfr[n] = *reinterpret_cast<const bf16x8*>(
                        (const char*)Bs + r*128 + (((kk*4 + fq) ^ (r & 7)) * 16));
                }
                #pragma unroll
                for (int m = 0; m < 4; m++)
                    #pragma unroll
                    for (int n = 0; n < FN; n++)
                        acc[m][n] = __builtin_amdgcn_mfma_f32_16x16x32_bf16(af[m], bfr[n], acc[m][n], 0, 0, 0);
            }
            __syncthreads();
        }
    };
    run_seg(A1, B1, K1);
    if constexpr (TWOK) run_seg(A2, B2, K2);

    // ---------- coalesced epilogue: 2 rounds of 64 rows through LDS ----------
    const bool isDelta = (EP == 4) ? (n0 < DH) : false;
    #pragma unroll
    for (int c = 0; c < 2; ++c) {
        if ((wave >> 1) == c) {          // the 2 waves owning rows [c*64, c*64+64)
            #pragma unroll
            for (int m = 0; m < 4; m++)
                #pragma unroll
                for (int n = 0; n < FN; n++) {
                    const int col = wc + n*16 + fr;
                    #pragma unroll
                    for (int j = 0; j < 4; j++)
                        ep[(m*16 + fq*4 + j)*EPS + col] = acc[m][n][j];
                }
        }
        __syncthreads();
        #pragma unroll
        for (int p = 0; p < BN/16; ++p) {
            const int idx = p*256 + tid;         // 16*BN float4 per round
            const int row = idx / (BN/4), c4 = idx % (BN/4);
            float4 v = *reinterpret_cast<const float4*>(&ep[row*EPS + c4*4]);
            const int rg   = m0 + c*64 + row;
            const int colg = n0 + c4*4;
            if constexpr (EP == 4) {
                const int cc = isDelta ? colg : (colg - DH);
                const float4 bv = *reinterpret_cast<const float4*>(
                    (isDelta ? bias : bias2) + cc);
                ushort4 o;
                if (isDelta) {
                    o.x = f2bf(softplus_fast(v.x + bv.x));
                    o.y = f2bf(softplus_fast(v.y + bv.y));
                    o.z = f2bf(softplus_fast(v.z + bv.z));
                    o.w = f2bf(softplus_fast(v.w + bv.w));
                } else {
                    o.x = f2bf(v.x + bv.x); o.y = f2bf(v.y + bv.y);
                    o.z = f2bf(v.z + bv.z); o.w = f2bf(v.w + bv.w);
                }
                *reinterpret_cast<ushort4*>((isDelta ? Cb : Cb2) + (size_t)rg*DH + cc) = o;
            } else {
                if (bias) {
                    const float4 b1 = *reinterpret_cast<const float4*>(bias + colg);
                    v.x += b1.x; v.y += b1.y; v.z += b1.z; v.w += b1.w;
                }
                if (bias2) {
                    const float4 b2 = *reinterpret_cast<const float4*>(bias2 + colg);
                    v.x += b2.x; v.y += b2.y; v.z += b2.z; v.w += b2.w;
                }
                const size_t gidx = (size_t)rg * N + colg;
                if constexpr (EP == 0) {
                    ushort4 o = { f2bf(v.x), f2bf(v.y), f2bf(v.z), f2bf(v.w) };
                    *reinterpret_cast<ushort4*>(Cb + gidx) = o;
                } else if constexpr (EP == 2) {
                    const ushort4 ab = *reinterpret_cast<const ushort4*>(aux + gidx);
                    ushort4 o = { f2bf(bf2f(ab.x) * silu_fast(v.x)),
                                  f2bf(bf2f(ab.y) * silu_fast(v.y)),
                                  f2bf(bf2f(ab.z) * silu_fast(v.z)),
                                  f2bf(bf2f(ab.w) * silu_fast(v.w)) };
                    *reinterpret_cast<ushort4*>(Cb + gidx) = o;
                } else {   // EP 3
                    const ushort4 ab = *reinterpret_cast<const ushort4*>(aux + gidx);
                    float4 o = { bf2f(ab.x) + v.x, bf2f(ab.y) + v.y,
                                 bf2f(ab.z) + v.z, bf2f(ab.w) + v.w };
                    *reinterpret_cast<float4*>(C + gidx) = o;
                }
            }
        }
        __syncthreads();
    }
}

// ---------------- depthwise conv3 (pad 1, per seq of 4096) + silu, bf16x8 ----------------
__global__ void conv_silu8(const u16* __restrict__ x1, const float* __restrict__ cw,
                           const float* __restrict__ cb, u16* __restrict__ xab) {
    int t = blockIdx.x * blockDim.x + threadIdx.x;
    int c8  = t & (DMODEL/8 - 1);
    int row = t >> 7;
    int l = row & (SEQ - 1);
    const int c0 = c8 * 8;
    const size_t i0 = (size_t)row * DMODEL + c0;
    bf16x8 v0 = *reinterpret_cast<const bf16x8*>(x1 + i0);
    bf16x8 vm = {}; if (l > 0)       vm = *reinterpret_cast<const bf16x8*>(x1 + i0 - DMODEL);
    bf16x8 vp = {}; if (l < SEQ - 1) vp = *reinterpret_cast<const bf16x8*>(x1 + i0 + DMODEL);
    if (l == 0)       vm = bf16x8{};
    if (l == SEQ - 1) vp = bf16x8{};
    bf16x8 o;
    #pragma unroll
    for (int j = 0; j < 8; ++j) {
        const int c = c0 + j;
        float v = cw[c*3+0]*bf2f((u16)vm[j]) + cw[c*3+1]*bf2f((u16)v0[j])
                + cw[c*3+2]*bf2f((u16)vp[j]) + cb[c];
        o[j] = (short)f2bf(silu_fast(v));
    }
    *reinterpret_cast<bf16x8*>(xab + i0) = o;
}

// ---------------- SSM chunked scan: 2 channels/thread via u32 loads (R16 form) --------
__global__ void scan_chunks(const u16* __restrict__ delta, const u16* __restrict__ pBv,
                            const float* __restrict__ Avec,
                            float* __restrict__ cA, float* __restrict__ cB) {
    const int c = (blockIdx.x * blockDim.x + threadIdx.x) * 2;
    const int q = blockIdx.y;
    const int b = blockIdx.z;
    const float A0 = Avec[c], A1 = Avec[c+1];
    float hA0 = 1.f, hB0 = 0.f, hA1 = 1.f, hB1 = 0.f;
    size_t base = ((size_t)b*SEQ + q*CHUNK)*DH + c;
    for (int j = 0; j < CHUNK; ++j) {
        const u32 du = *reinterpret_cast<const u32*>(delta + base);
        const u32 pu = *reinterpret_cast<const u32*>(pBv + base);
        const float d0 = bf2f((u16)(du & 0xFFFF)), d1 = bf2f((u16)(du >> 16));
        const float p0 = bf2f((u16)(pu & 0xFFFF)), p1 = bf2f((u16)(pu >> 16));
        const float a0 = __expf(d0 * A0), a1 = __expf(d1 * A1);
        hA0 *= a0; hB0 = a0*hB0 + d0*p0;
        hA1 *= a1; hB1 = a1*hB1 + d1*p1;
        base += DH;
    }
    size_t o = ((size_t)b*NCHUNK + q)*DH + c;
    cA[o] = hA0; cA[o+1] = hA1;
    cB[o] = hB0; cB[o+1] = hB1;
}

__global__ void scan_prefix(const float* __restrict__ cA, const float* __restrict__ cB,
                            float* __restrict__ cH) {
    const int t = blockIdx.x * blockDim.x + threadIdx.x;
    const int b = t >> 11;
    const int c = t & (DH - 1);
    float h = 0.f;
    size_t o = ((size_t)b*NCHUNK)*DH + c;
    float a = cA[o], bb = cB[o];
    for (int q = 0; q < NCHUNK; ++q) {
        const size_t on = o + DH;
        float a2 = 0.f, b2 = 0.f;
        if (q + 1 < NCHUNK) { a2 = cA[on]; b2 = cB[on]; }
        cH[o] = h;
        h = a*h + bb;
        a = a2; bb = b2; o = on;
    }
}

__global__ void scan_apply(const u16* __restrict__ delta, const u16* __restrict__ pBv,
                           const float* __restrict__ Avec, const float* __restrict__ cH,
                           u16* __restrict__ hstb) {
    const int c = (blockIdx.x * blockDim.x + threadIdx.x) * 2;
    const int q = blockIdx.y;
    const int b = blockIdx.z;
    const float A0 = Avec[c], A1 = Avec[c+1];
    const size_t oh = ((size_t)b*NCHUNK + q)*DH + c;
    float h0 = cH[oh], h1 = cH[oh+1];
    size_t base = ((size_t)b*SEQ + q*CHUNK)*DH + c;
    for (int j = 0; j < CHUNK; ++j) {
        const u32 du = *reinterpret_cast<const u32*>(delta + base);
        const u32 pu = *reinterpret_cast<const u32*>(pBv + base);
        const float d0 = bf2f((u16)(du & 0xFFFF)), d1 = bf2f((u16)(du >> 16));
        const float p0 = bf2f((u16)(pu & 0xFFFF)), p1 = bf2f((u16)(pu >> 16));
        const float a0 = __expf(d0 * A0), a1 = __expf(d1 * A1);
        h0 = a0*h0 + d0*p0;
        h1 = a1*h1 + d1*p1;
        const u32 hv = (u32)f2bf(h0) | ((u32)f2bf(h1) << 16);
        *reinterpret_cast<u32*>(hstb + base) = hv;
        base += DH;
    }
}

// ---------------- host ----------------
extern "C" void kernel_launch(void* const* d_in, const int* in_sizes, int n_in,
                              void* d_out, int out_size, void* d_ws, size_t ws_size,
                              hipStream_t stream) {
    const float* x      = (const float*)d_in[0];
    const float* W1     = (const float*)d_in[1];
    const float* conv_w = (const float*)d_in[2];
    const float* conv_b = (const float*)d_in[3];
    const float* Avec   = (const float*)d_in[4];
    const float* Wb     = (const float*)d_in[5];
    const float* bb     = (const float*)d_in[6];
    const float* Wc     = (const float*)d_in[7];
    const float* bc     = (const float*)d_in[8];
    const float* Wd     = (const float*)d_in[9];
    const float* bd     = (const float*)d_in[10];
    const float* Wdelta = (const float*)d_in[11];
    const float* bdelta = (const float*)d_in[12];
    const float* W2     = (const float*)d_in[13];
    const float* Wlast  = (const float*)d_in[14];
    float* out = (float*)d_out;
    (void)in_sizes; (void)n_in; (void)out_size;

    struct Ptrs {
        u16 *w1, *wdel, *wb, *wd, *wc, *w2, *wl;
        float *cA, *cB, *cH;
        u16 *xb, *x1b, *xab, *delta, *pBv, *ossb, *hstb, *zb;
        size_t total;
    };
    auto layout = [&](int passes) -> Ptrs {
        Ptrs P{};
        const size_t Mp = MROWS / passes;
        const int nb = BATCH / passes;
        size_t off = 0;
        auto al = [&](size_t bytes) -> char* {
            char* p = (char*)d_ws + off; off += (bytes + 255) & ~(size_t)255; return p;
        };
        P.w1   = (u16*)al((size_t)DMODEL*DMODEL*2);
        P.wdel = (u16*)al((size_t)DH*DMODEL*2);
        P.wb   = (u16*)al((size_t)DH*DMODEL*2);
        P.wd   = (u16*)al((size_t)DMODEL*DMODEL*2);
        P.wc   = (u16*)al((size_t)DMODEL*DH*2);
        P.w2   = (u16*)al((size_t)DMODEL*DMODEL*2);
        P.wl   = (u16*)al((size_t)DMODEL*DMODEL*2);
        P.cA  = (float*)al((size_t)nb*NCHUNK*DH*4);
        P.cB  = (float*)al((size_t)nb*NCHUNK*DH*4);
        P.cH  = (float*)al((size_t)nb*NCHUNK*DH*4);
        char* RA = al(Mp*DMODEL*2);                   // xb -> ossb
        char* RB = al(Mp*DMODEL*2);                   // x1b -> zb
        char* RC = al(Mp*DMODEL*2);                   // xab
        char* RD = al(Mp*DH*2);                       // delta
        char* RE = al(Mp*DH*2);                       // pBv
        char* RF = al(Mp*DH*2);                       // hstb
        P.xb    = (u16*)RA; P.ossb = (u16*)RA;
        P.x1b   = (u16*)RB; P.zb   = (u16*)RB;
        P.xab   = (u16*)RC;
        P.delta = (u16*)RD;
        P.pBv   = (u16*)RE;
        P.hstb  = (u16*)RF;
        P.total = off;
        return P;
    };

    int passes = (ws_size >= layout(1).total) ? 1 : 2;
    Ptrs P = layout(passes);
    if (ws_size < P.total) return;
    const int Mp = MROWS / passes;
    const int nb = BATCH / passes;

    const dim3 blk(256);

    // one fused launch: convert all 7 weights into dedicated slots
    {
        CvtArgs a{};
        const float* srcs[7] = { W1, Wdelta, Wb, Wd, Wc, W2, Wlast };
        u16* dsts[7] = { P.w1, P.wdel, P.wb, P.wd, P.wc, P.w2, P.wl };
        const unsigned n4s[7] = {
            DMODEL*DMODEL/4, DH*DMODEL/4, DH*DMODEL/4, DMODEL*DMODEL/4,
            DMODEL*DH/4, DMODEL*DMODEL/4, DMODEL*DMODEL/4 };
        unsigned cum = 0;
        for (int s = 0; s < 7; ++s) { a.src[s] = srcs[s]; a.dst[s] = dsts[s]; a.cum[s] = cum; cum += n4s[s]; }
        a.cum[7] = cum;
        cvt_multi<<<dim3((cum + 255)/256), blk, 0, stream>>>(a);
    }

    const dim3 gS (DMODEL/64,  Mp/128);   // BN=64 : 16 x 64 = 1024 blocks (4/CU)
    const dim3 gDB(2*DH/128,   Mp/128);   // BN=128: 32 x 64 = 2048 blocks (merged)

    for (int p = 0; p < passes; ++p) {
        const float* x_p  = x  + (size_t)p*Mp*DMODEL;
        float*      out_p = out + (size_t)p*Mp*DMODEL;

        {   // x -> bf16
            int n4 = (int)((size_t)Mp*DMODEL / 4);
            cvt_bf16<<<dim3((n4 + 255)/256), blk, 0, stream>>>(x_p, P.xb, n4);
        }
        // x1 = x @ W1^T
        gemm_bt<0,false,64><<<gS, blk, 0, stream>>>(P.xb, P.w1, DMODEL, nullptr, nullptr, 0,
                                                 nullptr, P.x1b, nullptr, nullptr, nullptr, nullptr, Mp, DMODEL);
        // xa = silu(conv3(x1))
        conv_silu8<<<dim3(Mp*DMODEL/8/256), blk, 0, stream>>>(P.x1b, conv_w, conv_b, P.xab);
        // merged: delta = softplus(xa@Wdelta^T + bdelta), pBv = xa@Wb^T + bb
        gemm_bt<4,false,128><<<gDB, blk, 0, stream>>>(P.xab, P.wdel, DMODEL, nullptr, nullptr, 0,
                                                  nullptr, P.delta, P.pBv, bdelta, bb, nullptr, Mp, 2*DH);
        // chunked scan -> h_st (bf16)
        scan_chunks<<<dim3(DH/2/256, NCHUNK, nb), blk, 0, stream>>>(P.delta, P.pBv, Avec, P.cA, P.cB);
        scan_prefix<<<dim3(nb*DH/256), blk, 0, stream>>>(P.cA, P.cB, P.cH);
        scan_apply <<<dim3(DH/2/256, NCHUNK, nb), blk, 0, stream>>>(P.delta, P.pBv, Avec, P.cH, P.hstb);
        // ossb = bf16(xa @ Wd^T + h_st @ Wc^T + bd + bc)
        gemm_bt<0,true,64><<<gS, blk, 0, stream>>>(P.xab, P.wd, DMODEL, P.hstb, P.wc, DH,
                                                nullptr, P.ossb, nullptr, bd, bc, nullptr, Mp, DMODEL);
        // z = ossb * silu(ossb @ W2^T)
        gemm_bt<2,false,64><<<gS, blk, 0, stream>>>(P.ossb, P.w2, DMODEL, nullptr, nullptr, 0,
                                                 nullptr, P.zb, nullptr, nullptr, nullptr, P.ossb, Mp, DMODEL);
        // out = ossb + z @ Wlast^T
        gemm_bt<3,false,64><<<gS, blk, 0, stream>>>(P.zb, P.wl, DMODEL, nullptr, nullptr, 0,
                                                 out_p, nullptr, nullptr, nullptr, nullptr, P.ossb, Mp, DMODEL);
    }
}